// Round 16
// baseline (253.569 us; speedup 1.0000x reference)
//
#include <hip/hip_runtime.h>

#define KCODES 512
#define DIM 64
#define NB 32
#define NH 64
#define NW 64
#define NPTS (NB*NH*NW)     // 131072
#define HW (NH*NW)          // 4096

// ---- output layout (floats) ----
#define O_OUT  0
#define O_LOSS 8388608
#define O_IDX  8388609
#define O_EMB  8519681
#define O_M    8552449
#define O_MM   8585217

// ---- workspace layout (floats) ----
#define W_DM   0                    // 32768
#define W_CNT  32768                // 512
#define W_LOSS 33280                // 1
#define W_SUMM 33281                // 1: sum of ema_M input
#define W_C    33282                // 512 codeword sq-norms
#define W_ZERO 33282                // memset extent (W_DM..W_SUMM)

#define XPAD 68
#define EPAD 68

// cnorm + side-effect: Sigma(ema_M) for the closed-form Ntot
__global__ void cnorm_kernel(const float* __restrict__ emb,
                             const float* __restrict__ emaM,
                             float* __restrict__ ws) {
    int k = blockIdx.x * blockDim.x + threadIdx.x;
    if (k >= KCODES) return;
    float s = 0.f;
    #pragma unroll
    for (int d = 0; d < DIM; ++d) { float v = emb[k*DIM + d]; s += v*v; }
    ws[W_C + k] = s;
    float m = emaM[k];
    #pragma unroll
    for (int off = 32; off >= 1; off >>= 1) m += __shfl_down(m, off, 64);
    if ((k & 63) == 0) atomicAdd(&ws[W_SUMM], m);
}

// r15 assign unchanged (133us, VGPR 100, WRITE 544KB, conflicts 0):
// register-tiled fp32 GEMM, 128 pts x 512 cw, 8x8 microtile, strict-< scan.
__global__ __launch_bounds__(256, 2) void assign_kernel(
    const float* __restrict__ enc, const float* __restrict__ emb,
    float* __restrict__ out, float* __restrict__ ws)
{
    __shared__ float XL[128*XPAD];   // [point][d]
    __shared__ float EL[128*EPAD];   // [cw][d]
    __shared__ float cnT[128];
    __shared__ int   bestI[128];

    const int t  = threadIdx.x;
    const int tx = t & 15;
    const int ty = t >> 4;
    const int wv = t >> 6, w = t & 63;
    const int R0 = blockIdx.x * 2;

    #pragma unroll
    for (int r2 = 0; r2 < 2; ++r2) {
        int R = R0 + r2, b = R >> 6, h = R & 63;
        const float* base = enc + (size_t)b*64*HW + (size_t)h*64 + w;
        int p = r2*64 + w;
        #pragma unroll
        for (int it = 0; it < 4; ++it) {
            int d0 = (it*4 + wv)*4;
            float4 v = make_float4(base[(size_t)(d0+0)*HW], base[(size_t)(d0+1)*HW],
                                   base[(size_t)(d0+2)*HW], base[(size_t)(d0+3)*HW]);
            *(float4*)(&XL[p*XPAD + d0]) = v;
        }
    }

    float best[8]; int bidx[8];
    #pragma unroll
    for (int i = 0; i < 8; ++i) { best[i] = 3.402823466e38f; bidx[i] = 0; }

    for (int tile = 0; tile < 4; ++tile) {
        __syncthreads();             // prior tile's EL reads done
        const float* esrc = emb + (size_t)tile*128*64;
        #pragma unroll
        for (int it = 0; it < 8; ++it) {
            int idx = t + it*256;
            *(float4*)(&EL[(idx >> 4)*EPAD + (idx & 15)*4]) =
                *(const float4*)(esrc + (idx >> 4)*64 + (idx & 15)*4);
        }
        if (t < 128) cnT[t] = ws[W_C + tile*128 + t];
        __syncthreads();

        float acc[8][8];
        #pragma unroll
        for (int i = 0; i < 8; ++i)
            #pragma unroll
            for (int j = 0; j < 8; ++j) acc[i][j] = 0.f;

        for (int c = 0; c < 16; ++c) {
            float4 xf[8], ef[8];
            #pragma unroll
            for (int i = 0; i < 8; ++i) {    // 4-address broadcast reads
                int p = 2*ty + (i&1) + 32*(i>>1);
                xf[i] = *(const float4*)(&XL[p*XPAD + c*4]);
            }
            #pragma unroll
            for (int j = 0; j < 8; ++j) {    // 2-way on bank quads = free
                int r = tx + 16*j;
                ef[j] = *(const float4*)(&EL[r*EPAD + c*4]);
            }
            #pragma unroll
            for (int i = 0; i < 8; ++i)
                #pragma unroll
                for (int j = 0; j < 8; ++j) {
                    acc[i][j] = fmaf(xf[i].x, ef[j].x, acc[i][j]);
                    acc[i][j] = fmaf(xf[i].y, ef[j].y, acc[i][j]);
                    acc[i][j] = fmaf(xf[i].z, ef[j].z, acc[i][j]);
                    acc[i][j] = fmaf(xf[i].w, ef[j].w, acc[i][j]);
                }
        }

        #pragma unroll
        for (int j = 0; j < 8; ++j) {
            int k = tile*128 + tx + 16*j;
            float cn = cnT[tx + 16*j];
            #pragma unroll
            for (int i = 0; i < 8; ++i) {
                float s = cn - 2.f*acc[i][j];
                if (s < best[i]) { best[i] = s; bidx[i] = k; }  // k strictly
            }                                                   // increasing
        }
    }

    #pragma unroll
    for (int i = 0; i < 8; ++i) {
        float b = best[i]; int kx = bidx[i];
        #pragma unroll
        for (int off = 1; off < 16; off <<= 1) {
            float ob = __shfl_xor(b, off, 64);
            int   ok = __shfl_xor(kx, off, 64);
            if (ob < b || (ob == b && ok < kx)) { b = ob; kx = ok; }
        }
        if (tx == 0) bestI[2*ty + (i&1) + 32*(i>>1)] = kx;
    }
    __syncthreads();
    if (t < 128) out[O_IDX + (size_t)R0*64 + t] = (float)bestI[t];
}

// scatter v4: dim-phased dmL (two 32-dim passes against [512][33] = 67.6KB)
// -> 2 blocks/CU (was 1 at [512][65]=135KB). 512 blocks x 4 rows, 16 waves:
// waves 0-7 accumulate (2 waves/row, 16 dims each/phase), waves 8-15 gather/
// store/loss. Flush-and-reset per phase: one 32-lane coalesced atomic run
// per nonzero row. Every (point,dim) visited exactly once -> sums bit-exact.
__global__ __launch_bounds__(1024, 2) void scatter_kernel(
    const float* __restrict__ enc, const float* __restrict__ emb,
    float* __restrict__ out, float* __restrict__ ws)
{
    __shared__ float dmL[KCODES][33];
    __shared__ float cntL[KCODES];
    __shared__ float redL[16];

    const int t  = threadIdx.x;
    const int w  = t & 63;
    const int wv = t >> 6;           // 0..15
    const int role = wv >> 3;        // 0: accumulate, 1: gather/store/loss
    const int rq = wv & 7;
    const int rw = rq >> 1;          // row slot 0..3
    const int q  = rq & 1;           // 16-dim sub-slot within phase
    const int pg = w >> 4, dl = w & 15;

    float* dmf = &dmL[0][0];
    for (int i = t; i < KCODES*33; i += 1024) dmf[i] = 0.f;
    if (t < KCODES) cntL[t] = 0.f;
    __syncthreads();

    const int R = blockIdx.x * 4 + rw;
    const int b = R >> 6, h = R & 63;
    const float* base  = enc + (size_t)b*(64*HW) + (size_t)h*64;
    float*       obase = out + O_OUT + (size_t)b*(64*HW) + (size_t)h*64;

    const int bidx = (int)out[O_IDX + (size_t)R*64 + w];
    float lsum = 0.f;

    #pragma unroll
    for (int phase = 0; phase < 2; ++phase) {
        if (role == 0) {
            if (phase == 0 && q == 0) atomicAdd(&cntL[bidx], 1.0f);  // once/pt
            #pragma unroll
            for (int jj = 0; jj < 16; ++jj) {
                int p  = jj*4 + pg;              // 4 pts x 16 dims per instr
                int kb = __shfl(bidx, p, 64);
                int d  = phase*32 + q*16 + dl;
                atomicAdd(&dmL[kb][d & 31], base[(size_t)d*HW + p]);
            }
        } else {
            #pragma unroll
            for (int jj = 0; jj < 16; ++jj) {
                int p  = jj*4 + pg;
                int kb = __shfl(bidx, p, 64);
                int d  = phase*32 + q*16 + dl;
                float xv = base[(size_t)d*HW + p];
                float qv = emb[kb*64 + d];       // 64B gather runs, L2-hot
                obase[(size_t)d*HW + p] = qv;
                float df = qv - xv;
                lsum = fmaf(df, df, lsum);
            }
        }
        __syncthreads();                         // phase accumulation done

        // flush-and-reset this 32-dim half: wave owns 32 rows, lanes<32 = dim
        for (int k = wv*32; k < wv*32 + 32; ++k) {
            float c = cntL[k];
            if (c == 0.f) continue;              // wave-uniform branch
            if (w < 32) {
                float v = dmL[k][w];
                dmL[k][w] = 0.f;                 // reset for next phase
                atomicAdd(&ws[W_DM + k*64 + phase*32 + w], v);
            }
            if (phase == 1 && w == 0) atomicAdd(&ws[W_CNT + k], c);
        }
        __syncthreads();                         // dmL clean before next phase
    }

    #pragma unroll
    for (int off = 32; off >= 1; off >>= 1) lsum += __shfl_down(lsum, off, 64);
    if (w == 0) redL[wv] = lsum;
    __syncthreads();
    if (t == 0) {
        float s = 0.f;
        #pragma unroll
        for (int v = 8; v < 16; ++v) s += redL[v];
        atomicAdd(&ws[W_LOSS], s);
    }
}

// Single fully-parallel finalize: Ntot closed form (0.99*SumEmaM + 0.01*NPTS)
__global__ void finalize_kernel(const float* __restrict__ emam,
                                const float* __restrict__ emaM,
                                float* __restrict__ out,
                                const float* __restrict__ ws)
{
    int i = blockIdx.x * blockDim.x + threadIdx.x;  // 0..32767
    int k = i >> 6;
    float Ntot = 0.99f * ws[W_SUMM] + 0.01f * (float)NPTS;
    float nM = 0.99f * emaM[k] + 0.01f * ws[W_CNT + k];
    float sm = (nM + 1e-5f) / (Ntot + 1e-5f * (float)KCODES) * Ntot;
    float nm = 0.99f * emam[i] + 0.01f * ws[W_DM + i];
    out[O_M + i] = nm;
    out[O_EMB + i] = nm / sm;
    if ((i & 63) == 0) out[O_MM + k] = sm;
    if (i == 0) out[O_LOSS] = 0.25f * ws[W_LOSS] / (float)((size_t)NPTS * DIM);
}

extern "C" void kernel_launch(void* const* d_in, const int* in_sizes, int n_in,
                              void* d_out, int out_size, void* d_ws, size_t ws_size,
                              hipStream_t stream)
{
    const float* enc  = (const float*)d_in[0];
    const float* emb  = (const float*)d_in[1];
    const float* emam = (const float*)d_in[2];
    const float* emaM = (const float*)d_in[3];
    float* out = (float*)d_out;
    float* ws  = (float*)d_ws;

    hipMemsetAsync(ws, 0, (size_t)W_ZERO * sizeof(float), stream);
    cnorm_kernel<<<2, 256, 0, stream>>>(emb, emaM, ws);
    assign_kernel<<<NPTS/128, 256, 0, stream>>>(enc, emb, out, ws);   // 1024 blocks
    scatter_kernel<<<512, 1024, 0, stream>>>(enc, emb, out, ws);      // 4 rows/blk
    finalize_kernel<<<(KCODES*DIM)/256, 256, 0, stream>>>(emam, emaM, out, ws);
}